// Round 20
// baseline (78.470 us; speedup 1.0000x reference)
//
#include <hip/hip_runtime.h>
#include <hip/hip_bf16.h>
#include <math.h>

// Problem constants (fixed instance)
#define E_EDGES 524288
#define NNODES  5120
#define KF      64
#define DF      128
#define FF      32
#define NPER    80    // nodes per batch (16 nuc + 64 elec)
#define NBUCK   (3 * NNODES)      // 15360 buckets (slot, node)
#define CAP     64                // rows per bucket (lambda=20.5 -> ~1e-15 overflow)
#define HXBLK   1280              // hx blocks (5120 nodes, 4 waves/block)
#define EBLK    2048              // edge blocks (256 edges each)

// workspace layout (bytes)
#define WS_CUR   0u
#define CUR_BYTES (NBUCK*4u)                        // 61,440 (zeroed per call)
#define WS_Z     CUR_BYTES
#define Z_BYTES  (NBUCK*KF*4u)                      // 3,932,160 (fully written)
#define WS_HX    (WS_Z + Z_BYTES)
#define HX_BYTES (NNODES*KF*4u)                     // 1,310,720
#define WS_AUX   (WS_HX + HX_BYTES)
#define AUX_BYTES (NBUCK*CAP*4u)                    // 3,932,160
#define WS_WO    (WS_AUX + AUX_BYTES)               // 9,236,480 (256-aligned)
#define WO_BYTES ((size_t)E_EDGES * KF * 2u)        // 67,108,864 (dense by edge)
#define WS_END   ((size_t)WS_WO + WO_BYTES)         // ~76 MB

typedef __attribute__((ext_vector_type(8))) short bf8_t;   // 8 bf16 (4 VGPRs)
typedef __attribute__((ext_vector_type(4))) float f4_t;    // MFMA 16x16 C/D

union U8 { bf8_t v; unsigned short u[8]; };
union B4 { bf8_t v; unsigned d[4]; };

// ssp(x) = softplus(x) - ln2, base-2 form (v_exp_f32/v_log_f32 are 2^x/log2x).
__device__ __forceinline__ float ssp_f(float x) {
    float t = exp2f(x * 1.4426950408889634f);
    return 0.6931471805599453f * (__log2f(1.0f + t) - 1.0f);
}

// hardware RNE f32->bf16
__device__ __forceinline__ unsigned short f2bf(float f) {
    union { __hip_bfloat16 h; unsigned short u; } c;
    c.h = __float2bfloat16(f);
    return c.u;
}
__device__ __forceinline__ float bf2f(unsigned short u) {
    union { unsigned u; float f; } c; c.u = ((unsigned)u) << 16;
    return c.f;
}

// ---- K1: zero the bucket cursors (61,440 B) ---------------------------------
__global__ void zero_k(float4* __restrict__ p)
{
    int i = blockIdx.x * blockDim.x + threadIdx.x;   // 15*256 = 3840 exact
    p[i] = make_float4(0.f, 0.f, 0.f, 0.f);
}

// ---- K2: fused hx build + block-sorted MFMA edge MLP, DENSE wo --------------
// wo is dense by global edge id -> tile stores depend only on reorder, NOT on
// the bucket cursor atomic. The returning atomicAdd merely records
// (e<<13)|sender into aux and completes UNDER the tile compute (no barrier
// after it) - moving the device-scope atomic off the block critical path.
__global__ __launch_bounds__(256, 6) void fused_k(
    const float* __restrict__ nuc, const float* __restrict__ elec,
    const float* __restrict__ hW, const float* __restrict__ hb,
    float* __restrict__ hx,
    const float* __restrict__ dist, const int* __restrict__ et,
    const int* __restrict__ snd, const int* __restrict__ recv,
    int* __restrict__ cur, unsigned* __restrict__ aux,
    unsigned short* __restrict__ wo,
    const float* __restrict__ w1_0, const float* __restrict__ b1_0,
    const float* __restrict__ w2_0, const float* __restrict__ b2_0,
    const float* __restrict__ w1_1, const float* __restrict__ b1_1,
    const float* __restrict__ w2_1, const float* __restrict__ b2_1,
    const float* __restrict__ w1_2, const float* __restrict__ b1_2,
    const float* __restrict__ w2_2, const float* __restrict__ b2_2)
{
    if (blockIdx.x < HXBLK) {
        // hx = concat(nuc, elec @ h_W + h_b), one wave per node
        int gw   = (blockIdx.x * 256 + threadIdx.x) >> 6;
        int lane = threadIdx.x & 63;
        int b = gw / NPER, p = gw % NPER;
        float v;
        if (p < 16) {
            v = nuc[((size_t)b * 16 + p) * KF + lane];
        } else {
            int pe = p - 16;
            const float* er = elec + ((size_t)b * 64 + pe) * DF;
            float acc = hb[lane];
            #pragma unroll 8
            for (int d = 0; d < DF; d++) acc = __fmaf_rn(er[d], hW[d * KF + lane], acc);
            v = acc;
        }
        hx[(size_t)gw * KF + lane] = v;
        return;
    }

    __shared__ unsigned short wlds[18 * 512];   // 18 KiB: pre-packed W frags
    __shared__ float blds[3][96];               // biases: b1[32] | b2[64]
    __shared__ unsigned short tlds[4][512];     // per-wave 16x32 bf16 tile
    __shared__ unsigned short reorder[320];     // block-sorted local edge ids
    __shared__ int scnt[4][3], sbase_w[4][3];
    __shared__ int seg_tile[3];                 // first tile index per slot
    __shared__ int tcount;

    const int tid = threadIdx.x, lane = tid & 63, wid = tid >> 6;
    const int l15 = lane & 15, l4 = lane >> 4;
    const int ebase = (blockIdx.x - HXBLK) * 256;
    const int e = ebase + tid;

    int etv = et[e], rv = recv[e], sv = snd[e];
    int slot = (etv == 3) ? 0 : (etv == 4) ? 1 : (etv == 1) ? 2 : -1;
    if ((rv % NPER) < 16) slot = -1;            // nuc receivers never read

    // ---- stage weights/biases, pad reorder ----
    {
        const float* W1s[3] = {w1_0, w1_1, w1_2};
        const float* W2s[3] = {w2_0, w2_1, w2_2};
        for (int f = wid; f < 18; f += 4) {
            int sg = f / 6, q = f % 6;
            const float* src = (q < 2) ? W1s[sg] : W2s[sg];
            int stride = (q < 2) ? 32 : 64;
            int cbase  = (q < 2) ? q * 16 : (q - 2) * 16;
            U8 pk;
            #pragma unroll
            for (int j = 0; j < 8; j++)
                pk.u[j] = f2bf(src[(l4 * 8 + j) * stride + cbase + l15]);
            *(bf8_t*)&wlds[f * 512 + lane * 8] = pk.v;
        }
        const float* B1s[3] = {b1_0, b1_1, b1_2};
        const float* B2s[3] = {b2_0, b2_1, b2_2};
        for (int i = tid; i < 288; i += 256) {
            int sg = i / 96, j = i % 96;
            blds[sg][j] = (j < 32) ? B1s[sg][j] : B2s[sg][j - 32];
        }
        for (int i = tid; i < 320; i += 256) reorder[i] = 0xFFFF;
    }
    // ---- block-local counting sort into 16-padded slot segments ----
    unsigned long long m0 = __ballot(slot == 0);
    unsigned long long m1 = __ballot(slot == 1);
    unsigned long long m2 = __ballot(slot == 2);
    if (lane == 0) {
        scnt[wid][0] = __popcll(m0); scnt[wid][1] = __popcll(m1); scnt[wid][2] = __popcll(m2);
    }
    __syncthreads();
    if (tid == 0) {
        int t = 0;
        for (int s = 0; s < 3; s++) {
            int b = 0;
            for (int w = 0; w < 4; w++) { sbase_w[w][s] = b; b += scnt[w][s]; }
            seg_tile[s] = t;
            t += (b + 15) >> 4;
        }
        tcount = t;                              // <= 19
    }
    __syncthreads();
    if (slot >= 0) {
        unsigned long long msel = (slot == 0) ? m0 : (slot == 1) ? m1 : m2;
        int rank = sbase_w[wid][slot] + __popcll(msel & ((1ull << lane) - 1ull));
        reorder[seg_tile[slot] * 16 + rank] = (unsigned short)tid;
    }
    __syncthreads();

    const int T = tcount;

    // ---- PREFETCH: issue ALL wave-tile A-frag loads up front (ILP) ----------
    bf8_t pa[5];
    int   pel[5], psl[5];                        // global edge id (or -1), slot
    #pragma unroll
    for (int k = 0; k < 5; k++) {
        int t  = wid + k * 4;
        bool on = t < T;
        int tt  = on ? t : 0;
        int s   = (tt >= seg_tile[2]) ? 2 : (tt >= seg_tile[1]) ? 1 : 0;
        int li  = on ? reorder[tt * 16 + l15] : 0xFFFF;
        int lie = (li == 0xFFFF) ? 0 : li;
        pel[k]  = (li == 0xFFFF) ? -1 : (ebase + lie);
        psl[k]  = s;
        const float* dp = dist + (size_t)(ebase + lie) * FF + l4 * 8;
        float4 v0 = *(const float4*)dp;
        float4 v1 = *(const float4*)(dp + 4);
        U8 pk;
        pk.u[0]=f2bf(v0.x); pk.u[1]=f2bf(v0.y); pk.u[2]=f2bf(v0.z); pk.u[3]=f2bf(v0.w);
        pk.u[4]=f2bf(v1.x); pk.u[5]=f2bf(v1.y); pk.u[6]=f2bf(v1.z); pk.u[7]=f2bf(v1.w);
        pa[k] = pk.v;
    }

    // ---- bucket record: returning atomic, OFF the critical path -------------
    // (nothing below depends on it; latency hides under tile compute)
    if (slot >= 0) {
        int bidx = slot * NNODES + rv;
        int p = atomicAdd(&cur[bidx], 1);
        if (p < CAP) aux[bidx * CAP + p] = ((unsigned)e << 13) | (unsigned)sv;
    }

    // ---- PROCESS: slot-pure 16x32 tiles --------------------------------------
    unsigned short* hs = tlds[wid];
    #pragma unroll
    for (int k = 0; k < 5; k++) {
        if (wid + k * 4 >= T) break;
        int s  = __builtin_amdgcn_readfirstlane(psl[k]);
        int el = pel[k];
        bf8_t a1 = pa[k];

        // layer 1: 2 MFMA, bias-initialized C
        f4_t c1[2];
        float bv0 = blds[s][l15], bv1 = blds[s][16 + l15];
        #pragma unroll
        for (int j = 0; j < 4; j++) { c1[0][j] = bv0; c1[1][j] = bv1; }
        #pragma unroll
        for (int n = 0; n < 2; n++) {
            bf8_t wf = *(bf8_t*)&wlds[(s * 6 + n) * 512 + lane * 8];
            c1[n] = __builtin_amdgcn_mfma_f32_16x16x32_bf16(a1, wf, c1[n], 0, 0, 0);
        }
        // ssp -> swizzled h tile (16x32 bf16)
        #pragma unroll
        for (int n = 0; n < 2; n++)
            #pragma unroll
            for (int r = 0; r < 4; r++) {
                int row = l4 * 4 + r, col = n * 16 + l15;
                hs[row * 32 + (((col >> 3) ^ (row & 3)) << 3) + (col & 7)] =
                    f2bf(ssp_f(c1[n][r]));
            }
        // layer-2 A-frag (h tile dead after this read)
        bf8_t ha = *(bf8_t*)&hs[l15 * 32 + ((l4 ^ (l15 & 3)) << 3)];

        // layer 2: two 32-col halves; hold both drains in regs
        bf8_t ov[2];
        #pragma unroll
        for (int nh = 0; nh < 2; nh++) {
            f4_t c2[2];
            float d0 = blds[s][32 + nh * 32 + l15];
            float d1 = blds[s][32 + nh * 32 + 16 + l15];
            #pragma unroll
            for (int j = 0; j < 4; j++) { c2[0][j] = d0; c2[1][j] = d1; }
            #pragma unroll
            for (int n = 0; n < 2; n++) {
                bf8_t wf = *(bf8_t*)&wlds[(s * 6 + 2 + nh * 2 + n) * 512 + lane * 8];
                c2[n] = __builtin_amdgcn_mfma_f32_16x16x32_bf16(ha, wf, c2[n], 0, 0, 0);
            }
            #pragma unroll
            for (int n = 0; n < 2; n++)
                #pragma unroll
                for (int r = 0; r < 4; r++) {
                    int row = l4 * 4 + r, col = n * 16 + l15;
                    hs[row * 32 + (((col >> 3) ^ (row & 3)) << 3) + (col & 7)] =
                        f2bf(c2[n][r]);
                }
            // same-wave DS ops are ordered: read before next nh clobbers tile
            ov[nh] = *(bf8_t*)&hs[l15 * 32 + ((l4 ^ (l15 & 3)) << 3)];
        }

        // ---- FULL-LINE drain to DENSE wo rows (address = global edge id) ----
        // Chunk q (16 B at halfword q*8) of tile-row r lives in lane
        // (l4=q&3, l15=r), register ov[q>>2]. Target lane L stores chunk
        // q=L&7 of row r=hf*8+(L>>3); source lane src=(L&3)*16+r.
        {
            B4 o0, o1; o0.v = ov[0]; o1.v = ov[1];
            const int qhi = (lane >> 2) & 1;
            #pragma unroll
            for (int hf = 0; hf < 2; hf++) {
                int r   = hf * 8 + (lane >> 3);
                int src = (lane & 3) * 16 + r;
                int elr = __shfl(el, src);
                B4 tv;
                #pragma unroll
                for (int d = 0; d < 4; d++) {
                    unsigned t0 = (unsigned)__shfl((int)o0.d[d], src);
                    unsigned t1 = (unsigned)__shfl((int)o1.d[d], src);
                    tv.d[d] = qhi ? t1 : t0;
                }
                if (elr >= 0)
                    *(uint4*)&wo[(size_t)elr * KF + (lane & 7) * 8] = *(uint4*)&tv.d[0];
            }
        }
    }
}

// ---- K3: one wave per bucket, 4-row vectorized streaming sum ----------------
__global__ __launch_bounds__(256, 8) void gather_k(
    const unsigned short* __restrict__ wo, const float* __restrict__ hx,
    const unsigned* __restrict__ aux, const int* __restrict__ cur,
    float* __restrict__ z)
{
    int wv   = blockIdx.x * 4 + (threadIdx.x >> 6);   // bucket
    int lane = threadIdx.x & 63;
    int ph   = lane >> 4;
    int cg   = lane & 15;
    int n    = cur[wv]; if (n > CAP) n = CAP;
    size_t base = (size_t)wv * CAP;
    float4 acc = make_float4(0.f, 0.f, 0.f, 0.f);
    for (int i = 0; i < n; i += 4) {
        bool on = (i + ph) < n;
        unsigned a = aux[base + i + (on ? ph : 0)];
        int sj = (int)(a & 8191u);
        size_t er = (size_t)(a >> 13) * KF;
        ushort4 w4 = *(const ushort4*)&wo[er + cg * 4];
        float4  h4 = *(const float4*)&hx[(size_t)sj * KF + cg * 4];
        if (on) {
            acc.x = __fmaf_rn(bf2f(w4.x), h4.x, acc.x);
            acc.y = __fmaf_rn(bf2f(w4.y), h4.y, acc.y);
            acc.z = __fmaf_rn(bf2f(w4.z), h4.z, acc.z);
            acc.w = __fmaf_rn(bf2f(w4.w), h4.w, acc.w);
        }
    }
    // reduce over the 4 row-phases (lanes differing in bits 4,5)
    acc.x += __shfl_xor(acc.x, 16); acc.y += __shfl_xor(acc.y, 16);
    acc.z += __shfl_xor(acc.z, 16); acc.w += __shfl_xor(acc.w, 16);
    acc.x += __shfl_xor(acc.x, 32); acc.y += __shfl_xor(acc.y, 32);
    acc.z += __shfl_xor(acc.z, 32); acc.w += __shfl_xor(acc.w, 32);
    if (ph == 0)
        *(float4*)&z[(size_t)wv * KF + cg * 4] = acc;
}

// ---- K4: out = elec + sum_s z_s[:,elec] @ gW_s + gb_s (high-TLP) ------------
__global__ __launch_bounds__(256, 4) void out_k(
    const float* __restrict__ elec, const float* __restrict__ z,
    const float* __restrict__ g0W, const float* __restrict__ g0b,
    const float* __restrict__ g1W, const float* __restrict__ g1b,
    const float* __restrict__ g2W, const float* __restrict__ g2b,
    float* __restrict__ out)
{
    __shared__ float zr[8 * 192];      // 6 KiB: 8 rows x 192 k
    const int tid = threadIdx.x;
    const int rb  = blockIdx.x * 8;    // 512 blocks x 8 elec rows

    // load z tile (coalesced float4)
    for (int u4 = tid; u4 < 8 * 48; u4 += 256) {
        int row = u4 / 48, kq = u4 % 48;
        int gr = rb + row;
        int node = (gr >> 6) * NPER + 16 + (gr & 63);
        int k = kq * 4, s = k >> 6, kk = k & 63;
        *(float4*)&zr[row * 192 + k] =
            *(const float4*)&z[((size_t)(s * NNODES + node)) * KF + kk];
    }
    __syncthreads();

    const int lane = tid & 63, wid = tid >> 6;
    const int r0 = wid * 2, r1 = r0 + 1;      // wave owns 2 rows
    const int d  = lane * 2;                  // float2 over DF=128

    float2 gb;
    gb.x = g0b[d]     + g1b[d]     + g2b[d];
    gb.y = g0b[d + 1] + g1b[d + 1] + g2b[d + 1];
    float2 e0 = *(const float2*)&elec[(size_t)(rb + r0) * DF + d];
    float2 e1 = *(const float2*)&elec[(size_t)(rb + r1) * DF + d];
    float2 a0 = make_float2(e0.x + gb.x, e0.y + gb.y);
    float2 a1 = make_float2(e1.x + gb.x, e1.y + gb.y);

    const float* Ws[3] = {g0W, g1W, g2W};
    #pragma unroll 1
    for (int s = 0; s < 3; s++) {
        const float* W = Ws[s];
        const float* zp0 = &zr[r0 * 192 + s * 64];
        const float* zp1 = &zr[r1 * 192 + s * 64];
        #pragma unroll 4
        for (int kk = 0; kk < 64; kk++) {
            float2 w = *(const float2*)&W[kk * DF + d];
            float z0 = zp0[kk], z1 = zp1[kk];
            a0.x = __fmaf_rn(z0, w.x, a0.x); a0.y = __fmaf_rn(z0, w.y, a0.y);
            a1.x = __fmaf_rn(z1, w.x, a1.x); a1.y = __fmaf_rn(z1, w.y, a1.y);
        }
    }
    *(float2*)&out[(size_t)(rb + r0) * DF + d] = a0;
    *(float2*)&out[(size_t)(rb + r1) * DF + d] = a1;
}

extern "C" void kernel_launch(void* const* d_in, const int* in_sizes, int n_in,
                              void* d_out, int out_size, void* d_ws, size_t ws_size,
                              hipStream_t stream)
{
    const float* nuc  = (const float*)d_in[0];
    const float* elec = (const float*)d_in[1];
    const float* dist = (const float*)d_in[2];
    const float* wsW1 = (const float*)d_in[3];
    const float* wsB1 = (const float*)d_in[4];
    const float* wsW2 = (const float*)d_in[5];
    const float* wsB2 = (const float*)d_in[6];
    const float* gsW  = (const float*)d_in[7];
    const float* gsB  = (const float*)d_in[8];
    const float* waW1 = (const float*)d_in[9];
    const float* waB1 = (const float*)d_in[10];
    const float* waW2 = (const float*)d_in[11];
    const float* waB2 = (const float*)d_in[12];
    const float* gaW  = (const float*)d_in[13];
    const float* gaB  = (const float*)d_in[14];
    const float* wnW1 = (const float*)d_in[15];
    const float* wnB1 = (const float*)d_in[16];
    const float* wnW2 = (const float*)d_in[17];
    const float* wnB2 = (const float*)d_in[18];
    const float* gnW  = (const float*)d_in[19];
    const float* gnB  = (const float*)d_in[20];
    const float* hW   = (const float*)d_in[21];
    const float* hb   = (const float*)d_in[22];
    const int* e_typ    = (const int*)d_in[23];
    const int* senders  = (const int*)d_in[24];
    const int* receivers= (const int*)d_in[25];
    float* out = (float*)d_out;

    char* ws = (char*)d_ws;
    int*      cur  = (int*)(ws + WS_CUR);
    float*    z    = (float*)(ws + WS_Z);
    float*    hx   = (float*)(ws + WS_HX);
    unsigned* aux  = (unsigned*)(ws + WS_AUX);
    unsigned short* wo = (unsigned short*)(ws + WS_WO);

    zero_k<<<dim3(15), dim3(256), 0, stream>>>((float4*)cur);

    fused_k<<<dim3(HXBLK + EBLK), dim3(256), 0, stream>>>(
        nuc, elec, hW, hb, hx,
        dist, e_typ, senders, receivers, cur, aux, wo,
        wsW1, wsB1, wsW2, wsB2,    // slot 0: same (et==3)
        waW1, waB1, waW2, waB2,    // slot 1: anti (et==4)
        wnW1, wnB1, wnW2, wnB2);   // slot 2: n    (et==1)

    gather_k<<<dim3(NBUCK / 4), dim3(256), 0, stream>>>(wo, hx, aux, cur, z);

    out_k<<<dim3(512), dim3(256), 0, stream>>>(elec, z, gsW, gsB, gaW, gaB,
                                               gnW, gnB, out);
}

// Round 21
// 76.000 us; speedup vs baseline: 1.0325x; 1.0325x over previous
//
#include <hip/hip_runtime.h>
#include <hip/hip_bf16.h>
#include <math.h>

// Problem constants (fixed instance)
#define E_EDGES 524288
#define NNODES  5120
#define KF      64
#define DF      128
#define FF      32
#define NPER    80    // nodes per batch (16 nuc + 64 elec)
#define NBUCK   (3 * NNODES)      // 15360 buckets (slot, node)
#define CAP     64                // rows per bucket (lambda=20.5 -> ~1e-15 overflow)
#define HXBLK   1280              // hx blocks (5120 nodes, 4 waves/block)
#define EBLK    2048              // edge blocks (256 edges each)

// workspace layout (bytes)
#define WS_CUR   0u
#define CUR_BYTES (NBUCK*4u)                        // 61,440 (zeroed per call)
#define WS_Z     CUR_BYTES
#define Z_BYTES  (NBUCK*KF*4u)                      // 3,932,160 (fully written)
#define WS_HX    (WS_Z + Z_BYTES)
#define HX_BYTES (NNODES*KF*4u)                     // 1,310,720
#define WS_SL    (WS_HX + HX_BYTES)
#define SL_BYTES (NBUCK*CAP*4u)                     // 3,932,160
#define WS_WO    (WS_SL + SL_BYTES)                 // 9,236,480 (256-aligned)
#define WO_BYTES ((size_t)NBUCK*CAP*KF*2u)          // 125,829,120
#define WS_END   ((size_t)WS_WO + WO_BYTES)         // ~135 MB

typedef __attribute__((ext_vector_type(8))) short bf8_t;   // 8 bf16 (4 VGPRs)
typedef __attribute__((ext_vector_type(4))) float f4_t;    // MFMA 16x16 C/D

union U8 { bf8_t v; unsigned short u[8]; };

// ssp(x) = softplus(x) - ln2, base-2 form (v_exp_f32/v_log_f32 are 2^x/log2x).
__device__ __forceinline__ float ssp_f(float x) {
    float t = exp2f(x * 1.4426950408889634f);
    return 0.6931471805599453f * (__log2f(1.0f + t) - 1.0f);
}

// hardware RNE f32->bf16
__device__ __forceinline__ unsigned short f2bf(float f) {
    union { __hip_bfloat16 h; unsigned short u; } c;
    c.h = __float2bfloat16(f);
    return c.u;
}
__device__ __forceinline__ float bf2f(unsigned short u) {
    union { unsigned u; float f; } c; c.u = ((unsigned)u) << 16;
    return c.f;
}

// ---- K1: zero the bucket cursors (61,440 B) ---------------------------------
__global__ void zero_k(float4* __restrict__ p)
{
    int i = blockIdx.x * blockDim.x + threadIdx.x;   // 15*256 = 3840 exact
    p[i] = make_float4(0.f, 0.f, 0.f, 0.f);
}

// ---- K2: fused hx build + block-sorted MFMA edge MLP + strided scatter ------
__global__ __launch_bounds__(256, 6) void fused_k(
    const float* __restrict__ nuc, const float* __restrict__ elec,
    const float* __restrict__ hW, const float* __restrict__ hb,
    float* __restrict__ hx,
    const float* __restrict__ dist, const int* __restrict__ et,
    const int* __restrict__ snd, const int* __restrict__ recv,
    int* __restrict__ cur, int* __restrict__ slist,
    unsigned short* __restrict__ wo,
    const float* __restrict__ w1_0, const float* __restrict__ b1_0,
    const float* __restrict__ w2_0, const float* __restrict__ b2_0,
    const float* __restrict__ w1_1, const float* __restrict__ b1_1,
    const float* __restrict__ w2_1, const float* __restrict__ b2_1,
    const float* __restrict__ w1_2, const float* __restrict__ b1_2,
    const float* __restrict__ w2_2, const float* __restrict__ b2_2)
{
    if (blockIdx.x < HXBLK) {
        // hx = concat(nuc, elec @ h_W + h_b), one wave per node
        int gw   = (blockIdx.x * 256 + threadIdx.x) >> 6;
        int lane = threadIdx.x & 63;
        int b = gw / NPER, p = gw % NPER;
        float v;
        if (p < 16) {
            v = nuc[((size_t)b * 16 + p) * KF + lane];
        } else {
            int pe = p - 16;
            const float* er = elec + ((size_t)b * 64 + pe) * DF;
            float acc = hb[lane];
            #pragma unroll 8
            for (int d = 0; d < DF; d++) acc = __fmaf_rn(er[d], hW[d * KF + lane], acc);
            v = acc;
        }
        hx[(size_t)gw * KF + lane] = v;
        return;
    }

    __shared__ unsigned short wlds[18 * 512];   // 18 KiB: pre-packed W frags
    __shared__ float blds[3][96];               // biases: b1[32] | b2[64]
    __shared__ unsigned short tlds[4][512];     // per-wave 16x32 bf16 tile
    __shared__ unsigned short reorder[320];     // block-sorted local edge ids
    __shared__ int parr[256];                   // per-local-edge wo row (or -1)
    __shared__ int scnt[4][3], sbase_w[4][3];
    __shared__ int seg_tile[3];                 // first tile index per slot
    __shared__ int tcount;

    const int tid = threadIdx.x, lane = tid & 63, wid = tid >> 6;
    const int l15 = lane & 15, l4 = lane >> 4;
    const int ebase = (blockIdx.x - HXBLK) * 256;
    const int e = ebase + tid;

    int etv = et[e], rv = recv[e], sv = snd[e];
    int slot = (etv == 3) ? 0 : (etv == 4) ? 1 : (etv == 1) ? 2 : -1;
    if ((rv % NPER) < 16) slot = -1;            // nuc receivers never read

    // ---- stage weights/biases, pad reorder ----
    {
        const float* W1s[3] = {w1_0, w1_1, w1_2};
        const float* W2s[3] = {w2_0, w2_1, w2_2};
        for (int f = wid; f < 18; f += 4) {
            int sg = f / 6, q = f % 6;
            const float* src = (q < 2) ? W1s[sg] : W2s[sg];
            int stride = (q < 2) ? 32 : 64;
            int cbase  = (q < 2) ? q * 16 : (q - 2) * 16;
            U8 pk;
            #pragma unroll
            for (int j = 0; j < 8; j++)
                pk.u[j] = f2bf(src[(l4 * 8 + j) * stride + cbase + l15]);
            *(bf8_t*)&wlds[f * 512 + lane * 8] = pk.v;
        }
        const float* B1s[3] = {b1_0, b1_1, b1_2};
        const float* B2s[3] = {b2_0, b2_1, b2_2};
        for (int i = tid; i < 288; i += 256) {
            int sg = i / 96, j = i % 96;
            blds[sg][j] = (j < 32) ? B1s[sg][j] : B2s[sg][j - 32];
        }
        for (int i = tid; i < 320; i += 256) reorder[i] = 0xFFFF;
    }
    // ---- block-local counting sort into 16-padded slot segments ----
    unsigned long long m0 = __ballot(slot == 0);
    unsigned long long m1 = __ballot(slot == 1);
    unsigned long long m2 = __ballot(slot == 2);
    if (lane == 0) {
        scnt[wid][0] = __popcll(m0); scnt[wid][1] = __popcll(m1); scnt[wid][2] = __popcll(m2);
    }
    __syncthreads();
    if (tid == 0) {
        int t = 0;
        for (int s = 0; s < 3; s++) {
            int b = 0;
            for (int w = 0; w < 4; w++) { sbase_w[w][s] = b; b += scnt[w][s]; }
            seg_tile[s] = t;
            t += (b + 15) >> 4;
        }
        tcount = t;                              // <= 19
    }
    __syncthreads();
    int wpos = -1;
    if (slot >= 0) {
        unsigned long long msel = (slot == 0) ? m0 : (slot == 1) ? m1 : m2;
        int rank = sbase_w[wid][slot] + __popcll(msel & ((1ull << lane) - 1ull));
        reorder[seg_tile[slot] * 16 + rank] = (unsigned short)tid;
        int bidx = slot * NNODES + rv;
        int p = atomicAdd(&cur[bidx], 1);
        if (p < CAP) { wpos = bidx * CAP + p; slist[wpos] = sv; }
    }
    parr[tid] = wpos;
    __syncthreads();

    const int T = tcount;

    // ---- PREFETCH: issue ALL wave-tile A-frag loads up front (ILP) ----------
    bf8_t pa[5];
    int   pwp[5], psl[5];
    #pragma unroll
    for (int k = 0; k < 5; k++) {
        int t  = wid + k * 4;
        bool on = t < T;
        int tt  = on ? t : 0;
        int s   = (tt >= seg_tile[2]) ? 2 : (tt >= seg_tile[1]) ? 1 : 0;
        int li  = on ? reorder[tt * 16 + l15] : 0xFFFF;
        int lie = (li == 0xFFFF) ? 0 : li;
        pwp[k]  = (li == 0xFFFF) ? -1 : parr[lie];
        psl[k]  = s;
        const float* dp = dist + (size_t)(ebase + lie) * FF + l4 * 8;
        float4 v0 = *(const float4*)dp;
        float4 v1 = *(const float4*)(dp + 4);
        U8 pk;
        pk.u[0]=f2bf(v0.x); pk.u[1]=f2bf(v0.y); pk.u[2]=f2bf(v0.z); pk.u[3]=f2bf(v0.w);
        pk.u[4]=f2bf(v1.x); pk.u[5]=f2bf(v1.y); pk.u[6]=f2bf(v1.z); pk.u[7]=f2bf(v1.w);
        pa[k] = pk.v;
    }

    // ---- PROCESS: slot-pure 16x32 tiles, operands from registers/LDS --------
    unsigned short* hs = tlds[wid];
    #pragma unroll
    for (int k = 0; k < 5; k++) {
        if (wid + k * 4 >= T) break;
        int s  = __builtin_amdgcn_readfirstlane(psl[k]);
        int wp = pwp[k];
        bf8_t a1 = pa[k];

        // layer 1: 2 MFMA, bias-initialized C
        f4_t c1[2];
        float bv0 = blds[s][l15], bv1 = blds[s][16 + l15];
        #pragma unroll
        for (int j = 0; j < 4; j++) { c1[0][j] = bv0; c1[1][j] = bv1; }
        #pragma unroll
        for (int n = 0; n < 2; n++) {
            bf8_t wf = *(bf8_t*)&wlds[(s * 6 + n) * 512 + lane * 8];
            c1[n] = __builtin_amdgcn_mfma_f32_16x16x32_bf16(a1, wf, c1[n], 0, 0, 0);
        }
        // ssp -> swizzled h tile (16x32 bf16)
        #pragma unroll
        for (int n = 0; n < 2; n++)
            #pragma unroll
            for (int r = 0; r < 4; r++) {
                int row = l4 * 4 + r, col = n * 16 + l15;
                hs[row * 32 + (((col >> 3) ^ (row & 3)) << 3) + (col & 7)] =
                    f2bf(ssp_f(c1[n][r]));
            }
        // layer-2 A-frag (h tile dead after this read)
        bf8_t ha = *(bf8_t*)&hs[l15 * 32 + ((l4 ^ (l15 & 3)) << 3)];

        // layer 2: two 32-col halves; hold both drains in regs and store
        // back-to-back (one clause) per wo row.
        bf8_t ov[2];
        #pragma unroll
        for (int nh = 0; nh < 2; nh++) {
            f4_t c2[2];
            float d0 = blds[s][32 + nh * 32 + l15];
            float d1 = blds[s][32 + nh * 32 + 16 + l15];
            #pragma unroll
            for (int j = 0; j < 4; j++) { c2[0][j] = d0; c2[1][j] = d1; }
            #pragma unroll
            for (int n = 0; n < 2; n++) {
                bf8_t wf = *(bf8_t*)&wlds[(s * 6 + 2 + nh * 2 + n) * 512 + lane * 8];
                c2[n] = __builtin_amdgcn_mfma_f32_16x16x32_bf16(ha, wf, c2[n], 0, 0, 0);
            }
            #pragma unroll
            for (int n = 0; n < 2; n++)
                #pragma unroll
                for (int r = 0; r < 4; r++) {
                    int row = l4 * 4 + r, col = n * 16 + l15;
                    hs[row * 32 + (((col >> 3) ^ (row & 3)) << 3) + (col & 7)] =
                        f2bf(c2[n][r]);
                }
            // same-wave DS ops are ordered: read before next nh clobbers tile
            ov[nh] = *(bf8_t*)&hs[l15 * 32 + ((l4 ^ (l15 & 3)) << 3)];
        }
        if (wp >= 0) {
            *(bf8_t*)&wo[(size_t)wp * KF + l4 * 8]      = ov[0];
            *(bf8_t*)&wo[(size_t)wp * KF + 32 + l4 * 8] = ov[1];
        }
    }
}

// ---- K3: one wave per bucket, 4-row vectorized streaming sum ----------------
__global__ __launch_bounds__(256, 8) void gather_k(
    const unsigned short* __restrict__ wo, const float* __restrict__ hx,
    const int* __restrict__ slist, const int* __restrict__ cur,
    float* __restrict__ z)
{
    int wv   = blockIdx.x * 4 + (threadIdx.x >> 6);   // bucket
    int lane = threadIdx.x & 63;
    int ph   = lane >> 4;
    int cg   = lane & 15;
    int n    = cur[wv]; if (n > CAP) n = CAP;
    size_t base = (size_t)wv * CAP;
    float4 acc = make_float4(0.f, 0.f, 0.f, 0.f);
    for (int i = 0; i < n; i += 4) {
        bool on = (i + ph) < n;
        size_t row = base + i + (on ? ph : 0);
        int sj = slist[row];
        ushort4 w4 = *(const ushort4*)&wo[row * KF + cg * 4];
        float4  h4 = *(const float4*)&hx[(size_t)sj * KF + cg * 4];
        if (on) {
            acc.x = __fmaf_rn(bf2f(w4.x), h4.x, acc.x);
            acc.y = __fmaf_rn(bf2f(w4.y), h4.y, acc.y);
            acc.z = __fmaf_rn(bf2f(w4.z), h4.z, acc.z);
            acc.w = __fmaf_rn(bf2f(w4.w), h4.w, acc.w);
        }
    }
    // reduce over the 4 row-phases (lanes differing in bits 4,5)
    acc.x += __shfl_xor(acc.x, 16); acc.y += __shfl_xor(acc.y, 16);
    acc.z += __shfl_xor(acc.z, 16); acc.w += __shfl_xor(acc.w, 16);
    acc.x += __shfl_xor(acc.x, 32); acc.y += __shfl_xor(acc.y, 32);
    acc.z += __shfl_xor(acc.z, 32); acc.w += __shfl_xor(acc.w, 32);
    if (ph == 0)
        *(float4*)&z[(size_t)wv * KF + cg * 4] = acc;
}

// ---- K4: out = elec + sum_s z_s[:,elec] @ gW_s + gb_s (high-TLP) ------------
__global__ __launch_bounds__(256, 4) void out_k(
    const float* __restrict__ elec, const float* __restrict__ z,
    const float* __restrict__ g0W, const float* __restrict__ g0b,
    const float* __restrict__ g1W, const float* __restrict__ g1b,
    const float* __restrict__ g2W, const float* __restrict__ g2b,
    float* __restrict__ out)
{
    __shared__ float zr[8 * 192];      // 6 KiB: 8 rows x 192 k
    const int tid = threadIdx.x;
    const int rb  = blockIdx.x * 8;    // 512 blocks x 8 elec rows

    // load z tile (coalesced float4)
    for (int u4 = tid; u4 < 8 * 48; u4 += 256) {
        int row = u4 / 48, kq = u4 % 48;
        int gr = rb + row;
        int node = (gr >> 6) * NPER + 16 + (gr & 63);
        int k = kq * 4, s = k >> 6, kk = k & 63;
        *(float4*)&zr[row * 192 + k] =
            *(const float4*)&z[((size_t)(s * NNODES + node)) * KF + kk];
    }
    __syncthreads();

    const int lane = tid & 63, wid = tid >> 6;
    const int r0 = wid * 2, r1 = r0 + 1;      // wave owns 2 rows
    const int d  = lane * 2;                  // float2 over DF=128

    float2 gb;
    gb.x = g0b[d]     + g1b[d]     + g2b[d];
    gb.y = g0b[d + 1] + g1b[d + 1] + g2b[d + 1];
    float2 e0 = *(const float2*)&elec[(size_t)(rb + r0) * DF + d];
    float2 e1 = *(const float2*)&elec[(size_t)(rb + r1) * DF + d];
    float2 a0 = make_float2(e0.x + gb.x, e0.y + gb.y);
    float2 a1 = make_float2(e1.x + gb.x, e1.y + gb.y);

    const float* Ws[3] = {g0W, g1W, g2W};
    #pragma unroll 1
    for (int s = 0; s < 3; s++) {
        const float* W = Ws[s];
        const float* zp0 = &zr[r0 * 192 + s * 64];
        const float* zp1 = &zr[r1 * 192 + s * 64];
        #pragma unroll 4
        for (int kk = 0; kk < 64; kk++) {
            float2 w = *(const float2*)&W[kk * DF + d];
            float z0 = zp0[kk], z1 = zp1[kk];
            a0.x = __fmaf_rn(z0, w.x, a0.x); a0.y = __fmaf_rn(z0, w.y, a0.y);
            a1.x = __fmaf_rn(z1, w.x, a1.x); a1.y = __fmaf_rn(z1, w.y, a1.y);
        }
    }
    *(float2*)&out[(size_t)(rb + r0) * DF + d] = a0;
    *(float2*)&out[(size_t)(rb + r1) * DF + d] = a1;
}

extern "C" void kernel_launch(void* const* d_in, const int* in_sizes, int n_in,
                              void* d_out, int out_size, void* d_ws, size_t ws_size,
                              hipStream_t stream)
{
    const float* nuc  = (const float*)d_in[0];
    const float* elec = (const float*)d_in[1];
    const float* dist = (const float*)d_in[2];
    const float* wsW1 = (const float*)d_in[3];
    const float* wsB1 = (const float*)d_in[4];
    const float* wsW2 = (const float*)d_in[5];
    const float* wsB2 = (const float*)d_in[6];
    const float* gsW  = (const float*)d_in[7];
    const float* gsB  = (const float*)d_in[8];
    const float* waW1 = (const float*)d_in[9];
    const float* waB1 = (const float*)d_in[10];
    const float* waW2 = (const float*)d_in[11];
    const float* waB2 = (const float*)d_in[12];
    const float* gaW  = (const float*)d_in[13];
    const float* gaB  = (const float*)d_in[14];
    const float* wnW1 = (const float*)d_in[15];
    const float* wnB1 = (const float*)d_in[16];
    const float* wnW2 = (const float*)d_in[17];
    const float* wnB2 = (const float*)d_in[18];
    const float* gnW  = (const float*)d_in[19];
    const float* gnB  = (const float*)d_in[20];
    const float* hW   = (const float*)d_in[21];
    const float* hb   = (const float*)d_in[22];
    const int* e_typ    = (const int*)d_in[23];
    const int* senders  = (const int*)d_in[24];
    const int* receivers= (const int*)d_in[25];
    float* out = (float*)d_out;

    char* ws = (char*)d_ws;
    int*   cur   = (int*)(ws + WS_CUR);
    float* z     = (float*)(ws + WS_Z);
    float* hx    = (float*)(ws + WS_HX);
    int*   slist = (int*)(ws + WS_SL);
    unsigned short* wo = (unsigned short*)(ws + WS_WO);

    zero_k<<<dim3(15), dim3(256), 0, stream>>>((float4*)cur);

    fused_k<<<dim3(HXBLK + EBLK), dim3(256), 0, stream>>>(
        nuc, elec, hW, hb, hx,
        dist, e_typ, senders, receivers, cur, slist, wo,
        wsW1, wsB1, wsW2, wsB2,    // slot 0: same (et==3)
        waW1, waB1, waW2, waB2,    // slot 1: anti (et==4)
        wnW1, wnB1, wnW2, wnB2);   // slot 2: n    (et==1)

    gather_k<<<dim3(NBUCK / 4), dim3(256), 0, stream>>>(wo, hx, slist, cur, z);

    out_k<<<dim3(512), dim3(256), 0, stream>>>(elec, z, gsW, gsB, gaW, gaB,
                                               gnW, gnB, out);
}